// Round 7
// baseline (399.794 us; speedup 1.0000x reference)
//
#include <hip/hip_runtime.h>
#include <hip/hip_bf16.h>
#include <math.h>

#define NF     128
#define HID    6
#define GP     8      // padded row stride for g (32B, two float4)
#define NC     10
#define NG     64
#define SLOTS  64     // ELL row capacity (deg ~ Poisson(32); P(deg>64) ~ 4e-7/node)
#define OVFCAP 8192

// bucket build params
#define BKT_SH    7
#define BKT_NODES 128
#define NBK_MAX   1024     // supports N <= 131072
#define EPB       4096     // edges per phase-1 block (256 thr x 16)
#define BCAP      5120     // per-bucket capacity (mean 4096, +16 sigma)
#define BOVFCAP   4096

__device__ __forceinline__ void add4(float4& a, const float4 b) {
    a.x += b.x; a.y += b.y; a.z += b.z; a.w += b.w;
}

// ---------------- phase 1: bin edges by dst>>7, rank-from-count, binary-search copy-out ----------------
__global__ __launch_bounds__(256) void bucket_scatter_kernel(
        const int* __restrict__ src, const int* __restrict__ dst, int E, int nbk,
        int* __restrict__ bucket_cursor, unsigned int* __restrict__ bucket_arr,
        int* __restrict__ bovf_meta, int2* __restrict__ bovf) {
    __shared__ int cntL[NBK_MAX];
    __shared__ int offs[NBK_MAX + 1];
    __shared__ int gb[NBK_MAX];
    __shared__ int wtot[4];
    __shared__ unsigned int stage[EPB];
    int tid = threadIdx.x;
    for (int k = tid; k < NBK_MAX; k += 256) cntL[k] = 0;
    __syncthreads();                                     // B1
    int e0 = blockIdx.x * EPB;
    int cnt_e = E - e0; if (cnt_e > EPB) cnt_e = EPB;
    int sreg[16], dreg[16], rank[16];
    // pass A: load edges + LDS-atomic rank (atomic return IS the local rank)
    if (cnt_e == EPB && (E & 3) == 0) {
        const int4* s4p = (const int4*)(src + e0);
        const int4* d4p = (const int4*)(dst + e0);
#pragma unroll
        for (int k = 0; k < 4; ++k) {
            int4 sv = s4p[k * 256 + tid];
            int4 dv = d4p[k * 256 + tid];
            sreg[4*k+0] = sv.x; sreg[4*k+1] = sv.y; sreg[4*k+2] = sv.z; sreg[4*k+3] = sv.w;
            dreg[4*k+0] = dv.x; dreg[4*k+1] = dv.y; dreg[4*k+2] = dv.z; dreg[4*k+3] = dv.w;
        }
#pragma unroll
        for (int k = 0; k < 16; ++k) rank[k] = atomicAdd(&cntL[dreg[k] >> BKT_SH], 1);
    } else {
#pragma unroll
        for (int k = 0; k < 16; ++k) {
            int e = e0 + k * 256 + tid;
            if (e < E) {
                dreg[k] = dst[e]; sreg[k] = src[e];
                rank[k] = atomicAdd(&cntL[dreg[k] >> BKT_SH], 1);
            } else dreg[k] = -1;
        }
    }
    __syncthreads();                                     // B2
    // exclusive scan over 1024 bucket counts: 4/thread + wave shfl-scan + wave-total combine
    int base = tid * 4;
    int c0 = cntL[base], c1 = cntL[base + 1], c2 = cntL[base + 2], c3 = cntL[base + 3];
    int tsum = c0 + c1 + c2 + c3;
    int lane = tid & 63, wv = tid >> 6;
    int v = tsum;
#pragma unroll
    for (int off = 1; off < 64; off <<= 1) {
        int u = __shfl_up(v, off);
        if (lane >= off) v += u;
    }
    if (lane == 63) wtot[wv] = v;
    __syncthreads();                                     // B3
    int wbase = 0;
    for (int w = 0; w < wv; ++w) wbase += wtot[w];
    int ex = wbase + v - tsum;
    offs[base]     = ex;
    offs[base + 1] = ex + c0;
    offs[base + 2] = ex + c0 + c1;
    offs[base + 3] = ex + c0 + c1 + c2;
    if (tid == 0) offs[NBK_MAX] = cnt_e;                 // sentinel
    // reserve global spans (one atomic per non-empty bucket per block)
    for (int bb = tid; bb < nbk; bb += 256) {
        int c = cntL[bb];
        if (c > 0) gb[bb] = atomicAdd(&bucket_cursor[bb], c);
    }
    __syncthreads();                                     // B4
    // pass B: direct-placed stage write (no second atomic)
#pragma unroll
    for (int k = 0; k < 16; ++k) {
        int d = dreg[k];
        if (d < 0) continue;
        int b = d >> BKT_SH;
        stage[offs[b] + rank[k]] =
            (unsigned int)(d & (BKT_NODES - 1)) | ((unsigned int)sreg[k] << BKT_SH);
    }
    __syncthreads();                                     // B5
    // copy out: bucket via binary search on offs (runs -> coalesced segments)
    for (int j = tid; j < cnt_e; j += 256) {
        unsigned int p = stage[j];
        int lo = 0, hi = NBK_MAX;
        while (hi - lo > 1) {
            int mid = (lo + hi) >> 1;
            if (offs[mid] <= j) lo = mid; else hi = mid;
        }
        int b = lo;
        int grel = gb[b] + (j - offs[b]);
        if (grel < BCAP) {
            bucket_arr[(size_t)b * BCAP + grel] = p;
        } else {  // bucket capacity overflow (~never)
            int d = (b << BKT_SH) | (int)(p & (BKT_NODES - 1));
            int s = (int)(p >> BKT_SH);
            int p2 = atomicAdd(bovf_meta, 1);
            if (p2 < BOVFCAP) bovf[p2] = make_int2(d, s);
        }
    }
}

// ---------------- phase 2: per-bucket ELL build in LDS, pruned coalesced dump + fused dinv ----------------
__global__ __launch_bounds__(256) void ell_build_kernel(
        const unsigned int* __restrict__ bucket_arr, const int* __restrict__ bucket_cursor,
        const int* __restrict__ bovf_meta, const int2* __restrict__ bovf,
        int* __restrict__ ell, int* __restrict__ cnt, float* __restrict__ dinv,
        int* __restrict__ ovf_meta, int* __restrict__ ovf_dst, int* __restrict__ ovf_src,
        int N) {
    __shared__ int ell_s[BKT_NODES * SLOTS];   // 32KB
    __shared__ int cur[BKT_NODES];
    int b = blockIdx.x;
    int tid = threadIdx.x;
    if (tid < BKT_NODES) cur[tid] = 0;
    __syncthreads();
    int bc = bucket_cursor[b];
    if (bc > BCAP) bc = BCAP;
    const unsigned int* ba = bucket_arr + (size_t)b * BCAP;
    for (int j = tid; j < bc; j += 256) {
        unsigned int p = ba[j];
        int r = (int)(p & (BKT_NODES - 1));
        int s = (int)(p >> BKT_SH);
        int slot = atomicAdd(&cur[r], 1);
        if (slot < SLOTS) {
            ell_s[r * SLOTS + slot] = s;
        } else {  // node degree overflow (~never)
            int d = (b << BKT_SH) + r;
            int q = atomicAdd(ovf_meta, 1);
            if (q < OVFCAP) { ovf_dst[q] = d; ovf_src[q] = s; }
        }
    }
    // fold in bucket-capacity overflow edges (list is ~always empty)
    int m = *bovf_meta;
    if (m > BOVFCAP) m = BOVFCAP;
    for (int t = tid; t < m; t += 256) {
        int2 e = bovf[t];
        if ((e.x >> BKT_SH) == b) {
            int r = e.x & (BKT_NODES - 1);
            int slot = atomicAdd(&cur[r], 1);
            if (slot < SLOTS) {
                ell_s[r * SLOTS + slot] = e.y;
            } else {
                int q = atomicAdd(ovf_meta, 1);
                if (q < OVFCAP) { ovf_dst[q] = e.x; ovf_src[q] = e.y; }
            }
        }
    }
    __syncthreads();
    int nid0 = b << BKT_SH;
    int rows = N - nid0; if (rows > BKT_NODES) rows = BKT_NODES;
    if (rows <= 0) return;
    int4* eg = (int4*)(ell + (size_t)nid0 * SLOTS);
    const int4* es = (const int4*)ell_s;
    // dump only occupied int4 chunks (gathers clamp reads past cnt)
    for (int k = tid; k < rows * (SLOTS / 4); k += 256) {
        int r = k >> 4;            // SLOTS/4 == 16 chunks per row
        int q = k & 15;
        int c = cur[r]; if (c > SLOTS) c = SLOTS;
        if (q * 4 < c) eg[k] = es[k];
    }
    for (int r = tid; r < rows; r += 256) {
        int deg = cur[r];
        cnt[nid0 + r] = deg;
        dinv[nid0 + r] = rsqrtf((float)deg + 1.0f);   // +1 self loop
    }
}

// ---------------- layer 1: g = dinv * (x @ W1), 8 lanes per node ----------------
__global__ __launch_bounds__(256) void layer1_kernel(const float* __restrict__ x,
                                                     const float* __restrict__ W,
                                                     const float* __restrict__ dinv,
                                                     float* __restrict__ g, int N) {
    __shared__ float sW[8 * 100];
    for (int idx = threadIdx.x; idx < NF * HID; idx += 256) {
        int s = idx / 96, r = idx % 96;
        int o = r / 16, j = r % 16;
        sW[s * 100 + o * 16 + j] = W[(s * 16 + j) * HID + o];
    }
    __syncthreads();
    int t = blockIdx.x * 256 + threadIdx.x;
    int i = t >> 3;
    int sub = t & 7;
    if (i >= N) return;
    const float4* xr = (const float4*)(x + (size_t)i * NF + sub * 16);
    float4 xv0 = xr[0], xv1 = xr[1], xv2 = xr[2], xv3 = xr[3];
    const float4* wr = (const float4*)(sW + sub * 100);
    float p[HID];
#pragma unroll
    for (int o = 0; o < HID; ++o) {
        float4 w0 = wr[o * 4 + 0], w1 = wr[o * 4 + 1], w2 = wr[o * 4 + 2], w3 = wr[o * 4 + 3];
        p[o] = xv0.x * w0.x + xv0.y * w0.y + xv0.z * w0.z + xv0.w * w0.w
             + xv1.x * w1.x + xv1.y * w1.y + xv1.z * w1.z + xv1.w * w1.w
             + xv2.x * w2.x + xv2.y * w2.y + xv2.z * w2.z + xv2.w * w2.w
             + xv3.x * w3.x + xv3.y * w3.y + xv3.z * w3.z + xv3.w * w3.w;
    }
#pragma unroll
    for (int m = 1; m < 8; m <<= 1) {
#pragma unroll
        for (int o = 0; o < HID; ++o) p[o] += __shfl_xor(p[o], m);
    }
    float dv = dinv[i];
    float4* g4 = (float4*)g;
    if (sub == 0) g4[2 * i]     = make_float4(dv * p[0], dv * p[1], dv * p[2], dv * p[3]);
    if (sub == 1) g4[2 * i + 1] = make_float4(dv * p[4], dv * p[5], 0.f, 0.f);
}

// ---------------- chunked ELL gather: sub-lane owns int4 chunks -> full ILP ----------------
// slots [4*sub, 4*sub+4) and [32+4*sub, 32+4*sub+4). Out-of-range entries clamped
// to a safe index (chunk[0]) and their adds predicated off.
__device__ __forceinline__ void gather8(int ne, const int* __restrict__ er,
                                        const float4* __restrict__ g4, int sub,
                                        float4& a0, float4& a1) {
#pragma unroll
    for (int r = 0; r < SLOTS / 32; ++r) {
        int base = r * 32 + sub * 4;
        if (base < ne) {
            int4 q = *(const int4*)(er + base);
            int s0 = q.x;
            int s1 = (base + 1 < ne) ? q.y : s0;
            int s2 = (base + 2 < ne) ? q.z : s0;
            int s3 = (base + 3 < ne) ? q.w : s0;
            float4 v00 = g4[2 * s0], v01 = g4[2 * s0 + 1];
            float4 v10 = g4[2 * s1], v11 = g4[2 * s1 + 1];
            float4 v20 = g4[2 * s2], v21 = g4[2 * s2 + 1];
            float4 v30 = g4[2 * s3], v31 = g4[2 * s3 + 1];
            add4(a0, v00); add4(a1, v01);
            if (base + 1 < ne) { add4(a0, v10); add4(a1, v11); }
            if (base + 2 < ne) { add4(a0, v20); add4(a1, v21); }
            if (base + 3 < ne) { add4(a0, v30); add4(a1, v31); }
        }
    }
}

// ---------------- fused: gather + epilogue (+ next matmul), 8 lanes per node ----------------
// PREP=0: gout = dinv * (relu(dinv*(sum+self)+b) @ W)
// PREP=1: gout = dinv *  relu(dinv*(sum+self)+b)
template<int PREP>
__global__ __launch_bounds__(256) void gcn_layer8_kernel(
        const int* __restrict__ cnt, const int* __restrict__ ell,
        const int* __restrict__ ovf_meta, const int* __restrict__ ovf_dst,
        const int* __restrict__ ovf_src, const float* __restrict__ dinv,
        const float* __restrict__ gin, float* __restrict__ gout,
        const float* __restrict__ W, const float* __restrict__ b, int N) {
    int t = blockIdx.x * 256 + threadIdx.x;
    int i = t >> 3;
    int sub = t & 7;
    if (i >= N) return;
    int n = cnt[i];
    int ne = n < SLOTS ? n : SLOTS;
    const float4* g4 = (const float4*)gin;
    const int* er = ell + (size_t)i * SLOTS;
    float4 a0 = make_float4(0.f, 0.f, 0.f, 0.f), a1 = a0;
    gather8(ne, er, g4, sub, a0, a1);
    // self-loop term, added exactly once across the subgroup
    if (sub == 0) add4(a0, g4[2 * i]);
    if (sub == 1) add4(a1, g4[2 * i + 1]);
    if (n > SLOTS && sub == 2) {  // ~never taken; correct fallback for deg>SLOTS
        int m = ovf_meta[0];
        m = m < OVFCAP ? m : OVFCAP;
        for (int tt = 0; tt < m; ++tt) {
            if (ovf_dst[tt] == i) {
                int s = ovf_src[tt];
                add4(a0, g4[2 * s]); add4(a1, g4[2 * s + 1]);
            }
        }
    }
    // butterfly over the 6 useful components (all 8 lanes end with the total)
    float s0 = a0.x, s1 = a0.y, s2 = a0.z, s3 = a0.w, s4 = a1.x, s5 = a1.y;
#pragma unroll
    for (int m = 1; m < 8; m <<= 1) {
        s0 += __shfl_xor(s0, m); s1 += __shfl_xor(s1, m); s2 += __shfl_xor(s2, m);
        s3 += __shfl_xor(s3, m); s4 += __shfl_xor(s4, m); s5 += __shfl_xor(s5, m);
    }
    float dv = dinv[i];
    float sum[HID] = { s0, s1, s2, s3, s4, s5 };
    float h[HID];
#pragma unroll
    for (int f = 0; f < HID; ++f) {
        float u = dv * sum[f] + b[f];
        h[f] = u > 0.0f ? u : 0.0f;
    }
    if (PREP) {
        if (sub == 0) ((float4*)gout)[2 * i]     = make_float4(dv * h[0], dv * h[1], dv * h[2], dv * h[3]);
        if (sub == 1) ((float4*)gout)[2 * i + 1] = make_float4(dv * h[4], dv * h[5], 0.f, 0.f);
    } else {
        float o[HID];
#pragma unroll
        for (int fo = 0; fo < HID; ++fo) {
            float s = 0.0f;
#pragma unroll
            for (int fi = 0; fi < HID; ++fi) s += h[fi] * W[fi * HID + fo];
            o[fo] = dv * s;
        }
        if (sub == 0) ((float4*)gout)[2 * i]     = make_float4(o[0], o[1], o[2], o[3]);
        if (sub == 1) ((float4*)gout)[2 * i + 1] = make_float4(o[4], o[5], 0.f, 0.f);
    }
}

// ---------------- pool: gather conv7 + Wf + relu + LDS mean-pool, 8 lanes per node ----------------
__global__ __launch_bounds__(256) void pool_kernel(
        const int* __restrict__ cnt, const int* __restrict__ ell,
        const int* __restrict__ ovf_meta, const int* __restrict__ ovf_dst,
        const int* __restrict__ ovf_src, const float* __restrict__ dinv,
        const float* __restrict__ gin, const int* __restrict__ batch,
        const float* __restrict__ Wf, const float* __restrict__ bf,
        float* __restrict__ pooled, float* __restrict__ gcnt, int N) {
    __shared__ float sp[NG * NC];
    __shared__ float sc[NG];
    __shared__ int srange[2];
    for (int k = threadIdx.x; k < NG * NC; k += 256) sp[k] = 0.0f;
    if (threadIdx.x < NG) sc[threadIdx.x] = 0.0f;
    int start = blockIdx.x * 32;           // 32 nodes per block (256 thr / 8)
    int endi = min(start + 32, N) - 1;
    if (threadIdx.x == 0) {
        srange[0] = batch[start];   // batch is sorted
        srange[1] = batch[endi];
    }
    __syncthreads();
    int t = blockIdx.x * 256 + threadIdx.x;
    int i = t >> 3;
    int sub = t & 7;
    if (i < N) {
        int n = cnt[i];
        int ne = n < SLOTS ? n : SLOTS;
        const float4* g4 = (const float4*)gin;
        const int* er = ell + (size_t)i * SLOTS;
        float4 a0 = make_float4(0.f, 0.f, 0.f, 0.f), a1 = a0;
        gather8(ne, er, g4, sub, a0, a1);
        if (sub == 0) add4(a0, g4[2 * i]);
        if (sub == 1) add4(a1, g4[2 * i + 1]);
        if (n > SLOTS && sub == 2) {
            int m = ovf_meta[0];
            m = m < OVFCAP ? m : OVFCAP;
            for (int tt = 0; tt < m; ++tt) {
                if (ovf_dst[tt] == i) {
                    int s = ovf_src[tt];
                    add4(a0, g4[2 * s]); add4(a1, g4[2 * s + 1]);
                }
            }
        }
        float s0 = a0.x, s1 = a0.y, s2 = a0.z, s3 = a0.w, s4 = a1.x, s5 = a1.y;
#pragma unroll
        for (int m = 1; m < 8; m <<= 1) {
            s0 += __shfl_xor(s0, m); s1 += __shfl_xor(s1, m); s2 += __shfl_xor(s2, m);
            s3 += __shfl_xor(s3, m); s4 += __shfl_xor(s4, m); s5 += __shfl_xor(s5, m);
        }
        if (sub == 0) {
            float dv = dinv[i];
            float u[HID] = { dv * s0, dv * s1, dv * s2, dv * s3, dv * s4, dv * s5 };
            int bg = batch[i];
#pragma unroll
            for (int c = 0; c < NC; ++c) {
                float v = bf[c];
#pragma unroll
                for (int f = 0; f < HID; ++f) v += u[f] * Wf[f * NC + c];
                v = v > 0.0f ? v : 0.0f;
                atomicAdd(&sp[bg * NC + c], v);
            }
            atomicAdd(&sc[bg], 1.0f);
        }
    }
    __syncthreads();
    int bmin = srange[0], bmax = srange[1];
    int rows = bmax - bmin + 1;
    for (int k = threadIdx.x; k < rows * NC; k += 256) {
        int r = bmin + k / NC, c = k % NC;
        float v = sp[r * NC + c];
        if (v != 0.0f) atomicAdd(&pooled[r * NC + c], v);
    }
    for (int k = threadIdx.x; k < rows; k += 256) {
        float v = sc[bmin + k];
        if (v != 0.0f) atomicAdd(&gcnt[bmin + k], v);
    }
}

// ---------------- mean + log_softmax ----------------
__global__ void logsm_kernel(const float* __restrict__ pooled, const float* __restrict__ gcnt,
                             float* __restrict__ out) {
    int gidx = threadIdx.x;
    if (gidx >= NG) return;
    float c = gcnt[gidx];
    c = c > 1.0f ? c : 1.0f;
    float v[NC];
    float m = -1e30f;
#pragma unroll
    for (int k = 0; k < NC; ++k) {
        v[k] = pooled[gidx * NC + k] / c;
        m = v[k] > m ? v[k] : m;
    }
    float s = 0.0f;
#pragma unroll
    for (int k = 0; k < NC; ++k) s += expf(v[k] - m);
    float ls = logf(s);
#pragma unroll
    for (int k = 0; k < NC; ++k) out[gidx * NC + k] = v[k] - m - ls;
}

extern "C" void kernel_launch(void* const* d_in, const int* in_sizes, int n_in,
                              void* d_out, int out_size, void* d_ws, size_t ws_size,
                              hipStream_t stream) {
    const float* x     = (const float*)d_in[0];
    const int*   ei    = (const int*)d_in[1];
    const int*   batch = (const int*)d_in[2];
    const float* W[7];
    const float* b[7];
    for (int l = 0; l < 7; ++l) {
        W[l] = (const float*)d_in[3 + 2 * l];
        b[l] = (const float*)d_in[4 + 2 * l];
    }
    const int N = in_sizes[2];
    const int E = in_sizes[1] / 2;
    const int nbk = (N + BKT_NODES - 1) >> BKT_SH;
    const int* src = ei;
    const int* dst = ei + E;
    float* out = (float*)d_out;

    // workspace layout (16B-aligned blocks)
    char* wp = (char*)d_ws;
    int* bucket_cursor = (int*)wp;  wp += (size_t)NBK_MAX * 4;
    int* ovf_meta  = (int*)wp;      wp += 16;
    int* bovf_meta = (int*)wp;      wp += 16;   // metas contiguous with cursor -> one memset
    int* ovf_dst   = (int*)wp;      wp += OVFCAP * 4;
    int* ovf_src   = (int*)wp;      wp += OVFCAP * 4;
    int2* bovf     = (int2*)wp;     wp += (size_t)BOVFCAP * 8;
    int* cnt       = (int*)wp;      wp += (((size_t)N * 4 + 15) & ~15ull);
    float* dinv    = (float*)wp;    wp += (((size_t)N * 4 + 15) & ~15ull);
    float* g_a     = (float*)wp;    wp += (size_t)N * GP * 4;
    float* g_b     = (float*)wp;    wp += (size_t)N * GP * 4;
    float* pooled  = (float*)wp;    wp += NG * NC * 4;
    float* gcnt    = (float*)wp;    wp += (((size_t)NG * 4 + 15) & ~15ull);
    int* ell       = (int*)wp;      wp += (size_t)N * SLOTS * 4;
    unsigned int* bucket_arr = (unsigned int*)wp;  wp += (size_t)nbk * BCAP * 4;

    hipMemsetAsync(bucket_cursor, 0, (size_t)NBK_MAX * 4 + 32, stream);  // + both metas
    hipMemsetAsync(pooled, 0, (NG * NC + NG) * sizeof(float), stream);

    const int BT = 256;
    int bn8 = ((size_t)N * 8 + BT - 1) / BT;
    int bp1 = (E + EPB - 1) / EPB;

    bucket_scatter_kernel<<<bp1, BT, 0, stream>>>(src, dst, E, nbk, bucket_cursor,
                                                  bucket_arr, bovf_meta, bovf);
    ell_build_kernel<<<nbk, BT, 0, stream>>>(bucket_arr, bucket_cursor, bovf_meta, bovf,
                                             ell, cnt, dinv, ovf_meta, ovf_dst, ovf_src, N);

    layer1_kernel<<<bn8, BT, 0, stream>>>(x, W[0], dinv, g_a, N);

    // 5 mid layers: (b1,W2) .. (b5,W6), alternating g buffers
    gcn_layer8_kernel<0><<<bn8, BT, 0, stream>>>(cnt, ell, ovf_meta, ovf_dst, ovf_src, dinv, g_a, g_b, W[1], b[0], N);
    gcn_layer8_kernel<0><<<bn8, BT, 0, stream>>>(cnt, ell, ovf_meta, ovf_dst, ovf_src, dinv, g_b, g_a, W[2], b[1], N);
    gcn_layer8_kernel<0><<<bn8, BT, 0, stream>>>(cnt, ell, ovf_meta, ovf_dst, ovf_src, dinv, g_a, g_b, W[3], b[2], N);
    gcn_layer8_kernel<0><<<bn8, BT, 0, stream>>>(cnt, ell, ovf_meta, ovf_dst, ovf_src, dinv, g_b, g_a, W[4], b[3], N);
    gcn_layer8_kernel<0><<<bn8, BT, 0, stream>>>(cnt, ell, ovf_meta, ovf_dst, ovf_src, dinv, g_a, g_b, W[5], b[4], N);
    // layer 6 epilogue (b6), no next W
    gcn_layer8_kernel<1><<<bn8, BT, 0, stream>>>(cnt, ell, ovf_meta, ovf_dst, ovf_src, dinv, g_b, g_a, nullptr, b[5], N);
    // conv7 gather + Wf + bf + relu + pool
    pool_kernel<<<bn8, BT, 0, stream>>>(cnt, ell, ovf_meta, ovf_dst, ovf_src, dinv, g_a, batch, W[6], b[6], pooled, gcnt, N);
    logsm_kernel<<<1, 64, 0, stream>>>(pooled, gcnt, out);
}

// Round 8
// 353.498 us; speedup vs baseline: 1.1310x; 1.1310x over previous
//
#include <hip/hip_runtime.h>
#include <hip/hip_bf16.h>
#include <hip/hip_fp16.h>
#include <math.h>

#define NF     128
#define HID    6
#define NC     10
#define NG     64
#define SLOTS  64     // ELL row capacity (deg ~ Poisson(32); P(deg>64) ~ 4e-7/node)
#define OVFCAP 8192

// bucket build params
#define BKT_SH    7
#define BKT_NODES 128
#define NBK_MAX   1024     // supports N <= 131072
#define EPB       4096     // edges per phase-1 block (256 thr x 16)
#define BCAP      5120     // per-bucket capacity (mean 4096, +16 sigma)
#define BOVFCAP   4096

// g row: 6 values as fp16, padded to 16B (8 halves) -> ONE dwordx4 per neighbor
__device__ __forceinline__ void addh(float* a, uint4 q) {
    const __half2* h = (const __half2*)&q;
    float2 f0 = __half22float2(h[0]);
    float2 f1 = __half22float2(h[1]);
    float2 f2 = __half22float2(h[2]);
    a[0] += f0.x; a[1] += f0.y; a[2] += f1.x;
    a[3] += f1.y; a[4] += f2.x; a[5] += f2.y;
}

__device__ __forceinline__ uint4 packh(const float* v) {
    uint4 q;
    __half2* h = (__half2*)&q;
    h[0] = __floats2half2_rn(v[0], v[1]);
    h[1] = __floats2half2_rn(v[2], v[3]);
    h[2] = __floats2half2_rn(v[4], v[5]);
    h[3] = __floats2half2_rn(0.f, 0.f);
    return q;
}

// ---------------- phase 1: bin edges by dst>>7, rank-from-count, binary-search copy-out ----------------
__global__ __launch_bounds__(256) void bucket_scatter_kernel(
        const int* __restrict__ src, const int* __restrict__ dst, int E, int nbk,
        int* __restrict__ bucket_cursor, unsigned int* __restrict__ bucket_arr,
        int* __restrict__ bovf_meta, int2* __restrict__ bovf) {
    __shared__ int cntL[NBK_MAX];
    __shared__ int offs[NBK_MAX + 1];
    __shared__ int gb[NBK_MAX];
    __shared__ int wtot[4];
    __shared__ unsigned int stage[EPB];
    int tid = threadIdx.x;
    for (int k = tid; k < NBK_MAX; k += 256) cntL[k] = 0;
    __syncthreads();                                     // B1
    int e0 = blockIdx.x * EPB;
    int cnt_e = E - e0; if (cnt_e > EPB) cnt_e = EPB;
    int sreg[16], dreg[16], rank[16];
    // pass A: load edges + LDS-atomic rank (atomic return IS the local rank)
    if (cnt_e == EPB && (E & 3) == 0) {
        const int4* s4p = (const int4*)(src + e0);
        const int4* d4p = (const int4*)(dst + e0);
#pragma unroll
        for (int k = 0; k < 4; ++k) {
            int4 sv = s4p[k * 256 + tid];
            int4 dv = d4p[k * 256 + tid];
            sreg[4*k+0] = sv.x; sreg[4*k+1] = sv.y; sreg[4*k+2] = sv.z; sreg[4*k+3] = sv.w;
            dreg[4*k+0] = dv.x; dreg[4*k+1] = dv.y; dreg[4*k+2] = dv.z; dreg[4*k+3] = dv.w;
        }
#pragma unroll
        for (int k = 0; k < 16; ++k) rank[k] = atomicAdd(&cntL[dreg[k] >> BKT_SH], 1);
    } else {
#pragma unroll
        for (int k = 0; k < 16; ++k) {
            int e = e0 + k * 256 + tid;
            if (e < E) {
                dreg[k] = dst[e]; sreg[k] = src[e];
                rank[k] = atomicAdd(&cntL[dreg[k] >> BKT_SH], 1);
            } else dreg[k] = -1;
        }
    }
    __syncthreads();                                     // B2
    // exclusive scan over 1024 bucket counts: 4/thread + wave shfl-scan + wave-total combine
    int base = tid * 4;
    int c0 = cntL[base], c1 = cntL[base + 1], c2 = cntL[base + 2], c3 = cntL[base + 3];
    int tsum = c0 + c1 + c2 + c3;
    int lane = tid & 63, wv = tid >> 6;
    int v = tsum;
#pragma unroll
    for (int off = 1; off < 64; off <<= 1) {
        int u = __shfl_up(v, off);
        if (lane >= off) v += u;
    }
    if (lane == 63) wtot[wv] = v;
    __syncthreads();                                     // B3
    int wbase = 0;
    for (int w = 0; w < wv; ++w) wbase += wtot[w];
    int ex = wbase + v - tsum;
    offs[base]     = ex;
    offs[base + 1] = ex + c0;
    offs[base + 2] = ex + c0 + c1;
    offs[base + 3] = ex + c0 + c1 + c2;
    if (tid == 0) offs[NBK_MAX] = cnt_e;                 // sentinel
    // reserve global spans (one atomic per non-empty bucket per block)
    for (int bb = tid; bb < nbk; bb += 256) {
        int c = cntL[bb];
        if (c > 0) gb[bb] = atomicAdd(&bucket_cursor[bb], c);
    }
    __syncthreads();                                     // B4
    // pass B: direct-placed stage write (no second atomic)
#pragma unroll
    for (int k = 0; k < 16; ++k) {
        int d = dreg[k];
        if (d < 0) continue;
        int b = d >> BKT_SH;
        stage[offs[b] + rank[k]] =
            (unsigned int)(d & (BKT_NODES - 1)) | ((unsigned int)sreg[k] << BKT_SH);
    }
    __syncthreads();                                     // B5
    // copy out: bucket via binary search on offs (runs -> coalesced segments)
    for (int j = tid; j < cnt_e; j += 256) {
        unsigned int p = stage[j];
        int lo = 0, hi = NBK_MAX;
        while (hi - lo > 1) {
            int mid = (lo + hi) >> 1;
            if (offs[mid] <= j) lo = mid; else hi = mid;
        }
        int b = lo;
        int grel = gb[b] + (j - offs[b]);
        if (grel < BCAP) {
            bucket_arr[(size_t)b * BCAP + grel] = p;
        } else {  // bucket capacity overflow (~never)
            int d = (b << BKT_SH) | (int)(p & (BKT_NODES - 1));
            int s = (int)(p >> BKT_SH);
            int p2 = atomicAdd(bovf_meta, 1);
            if (p2 < BOVFCAP) bovf[p2] = make_int2(d, s);
        }
    }
}

// ---------------- phase 2: per-bucket ELL build in LDS, pruned coalesced dump + fused dinv ----------------
__global__ __launch_bounds__(256) void ell_build_kernel(
        const unsigned int* __restrict__ bucket_arr, const int* __restrict__ bucket_cursor,
        const int* __restrict__ bovf_meta, const int2* __restrict__ bovf,
        int* __restrict__ ell, int* __restrict__ cnt, float* __restrict__ dinv,
        int* __restrict__ ovf_meta, int* __restrict__ ovf_dst, int* __restrict__ ovf_src,
        int N) {
    __shared__ int ell_s[BKT_NODES * SLOTS];   // 32KB
    __shared__ int cur[BKT_NODES];
    int b = blockIdx.x;
    int tid = threadIdx.x;
    if (tid < BKT_NODES) cur[tid] = 0;
    __syncthreads();
    int bc = bucket_cursor[b];
    if (bc > BCAP) bc = BCAP;
    const unsigned int* ba = bucket_arr + (size_t)b * BCAP;
    for (int j = tid; j < bc; j += 256) {
        unsigned int p = ba[j];
        int r = (int)(p & (BKT_NODES - 1));
        int s = (int)(p >> BKT_SH);
        int slot = atomicAdd(&cur[r], 1);
        if (slot < SLOTS) {
            ell_s[r * SLOTS + slot] = s;
        } else {  // node degree overflow (~never)
            int d = (b << BKT_SH) + r;
            int q = atomicAdd(ovf_meta, 1);
            if (q < OVFCAP) { ovf_dst[q] = d; ovf_src[q] = s; }
        }
    }
    // fold in bucket-capacity overflow edges (list is ~always empty)
    int m = *bovf_meta;
    if (m > BOVFCAP) m = BOVFCAP;
    for (int t = tid; t < m; t += 256) {
        int2 e = bovf[t];
        if ((e.x >> BKT_SH) == b) {
            int r = e.x & (BKT_NODES - 1);
            int slot = atomicAdd(&cur[r], 1);
            if (slot < SLOTS) {
                ell_s[r * SLOTS + slot] = e.y;
            } else {
                int q = atomicAdd(ovf_meta, 1);
                if (q < OVFCAP) { ovf_dst[q] = e.x; ovf_src[q] = e.y; }
            }
        }
    }
    __syncthreads();
    int nid0 = b << BKT_SH;
    int rows = N - nid0; if (rows > BKT_NODES) rows = BKT_NODES;
    if (rows <= 0) return;
    int4* eg = (int4*)(ell + (size_t)nid0 * SLOTS);
    const int4* es = (const int4*)ell_s;
    // dump only occupied int4 chunks (gathers clamp reads past cnt)
    for (int k = tid; k < rows * (SLOTS / 4); k += 256) {
        int r = k >> 4;            // SLOTS/4 == 16 chunks per row
        int q = k & 15;
        int c = cur[r]; if (c > SLOTS) c = SLOTS;
        if (q * 4 < c) eg[k] = es[k];
    }
    for (int r = tid; r < rows; r += 256) {
        int deg = cur[r];
        cnt[nid0 + r] = deg;
        dinv[nid0 + r] = rsqrtf((float)deg + 1.0f);   // +1 self loop
    }
}

// ---------------- layer 1: g = dinv * (x @ W1), 8 lanes per node, fp16 row out ----------------
__global__ __launch_bounds__(256) void layer1_kernel(const float* __restrict__ x,
                                                     const float* __restrict__ W,
                                                     const float* __restrict__ dinv,
                                                     uint4* __restrict__ g16, int N) {
    __shared__ float sW[8 * 100];
    for (int idx = threadIdx.x; idx < NF * HID; idx += 256) {
        int s = idx / 96, r = idx % 96;
        int o = r / 16, j = r % 16;
        sW[s * 100 + o * 16 + j] = W[(s * 16 + j) * HID + o];
    }
    __syncthreads();
    int t = blockIdx.x * 256 + threadIdx.x;
    int i = t >> 3;
    int sub = t & 7;
    if (i >= N) return;
    const float4* xr = (const float4*)(x + (size_t)i * NF + sub * 16);
    float4 xv0 = xr[0], xv1 = xr[1], xv2 = xr[2], xv3 = xr[3];
    const float4* wr = (const float4*)(sW + sub * 100);
    float p[HID];
#pragma unroll
    for (int o = 0; o < HID; ++o) {
        float4 w0 = wr[o * 4 + 0], w1 = wr[o * 4 + 1], w2 = wr[o * 4 + 2], w3 = wr[o * 4 + 3];
        p[o] = xv0.x * w0.x + xv0.y * w0.y + xv0.z * w0.z + xv0.w * w0.w
             + xv1.x * w1.x + xv1.y * w1.y + xv1.z * w1.z + xv1.w * w1.w
             + xv2.x * w2.x + xv2.y * w2.y + xv2.z * w2.z + xv2.w * w2.w
             + xv3.x * w3.x + xv3.y * w3.y + xv3.z * w3.z + xv3.w * w3.w;
    }
#pragma unroll
    for (int m = 1; m < 8; m <<= 1) {
#pragma unroll
        for (int o = 0; o < HID; ++o) p[o] += __shfl_xor(p[o], m);
    }
    if (sub == 0) {
        float dv = dinv[i];
        float v[HID];
#pragma unroll
        for (int o = 0; o < HID; ++o) v[o] = dv * p[o];
        g16[i] = packh(v);
    }
}

// ---------------- chunked ELL gather (fp16 rows): 1 load per neighbor ----------------
// sub-lane owns slots [4*sub,4*sub+4) and [32+4*sub,...). Out-of-range entries
// clamped to chunk[0]; their adds predicated off.
__device__ __forceinline__ void gather8h(int ne, const int* __restrict__ er,
                                         const uint4* __restrict__ g16, int sub,
                                         float* acc) {
#pragma unroll
    for (int r = 0; r < SLOTS / 32; ++r) {
        int base = r * 32 + sub * 4;
        if (base < ne) {
            int4 q = *(const int4*)(er + base);
            int s0 = q.x;
            int s1 = (base + 1 < ne) ? q.y : s0;
            int s2 = (base + 2 < ne) ? q.z : s0;
            int s3 = (base + 3 < ne) ? q.w : s0;
            uint4 v0 = g16[s0];
            uint4 v1 = g16[s1];
            uint4 v2 = g16[s2];
            uint4 v3 = g16[s3];
            addh(acc, v0);
            if (base + 1 < ne) addh(acc, v1);
            if (base + 2 < ne) addh(acc, v2);
            if (base + 3 < ne) addh(acc, v3);
        }
    }
}

// ---------------- fused: gather + epilogue (+ next matmul), 8 lanes per node ----------------
// PREP=0: gout = dinv * (relu(dinv*(sum+self)+b) @ W)
// PREP=1: gout = dinv *  relu(dinv*(sum+self)+b)
template<int PREP>
__global__ __launch_bounds__(256) void gcn_layer8_kernel(
        const int* __restrict__ cnt, const int* __restrict__ ell,
        const int* __restrict__ ovf_meta, const int* __restrict__ ovf_dst,
        const int* __restrict__ ovf_src, const float* __restrict__ dinv,
        const uint4* __restrict__ gin, uint4* __restrict__ gout,
        const float* __restrict__ W, const float* __restrict__ b, int N) {
    int t = blockIdx.x * 256 + threadIdx.x;
    int i = t >> 3;
    int sub = t & 7;
    if (i >= N) return;
    int n = cnt[i];
    int ne = n < SLOTS ? n : SLOTS;
    const int* er = ell + (size_t)i * SLOTS;
    float acc[HID] = {0.f, 0.f, 0.f, 0.f, 0.f, 0.f};
    gather8h(ne, er, gin, sub, acc);
    // self-loop term, added exactly once across the subgroup
    if (sub == 0) addh(acc, gin[i]);
    if (n > SLOTS && sub == 2) {  // ~never taken; correct fallback for deg>SLOTS
        int m = ovf_meta[0];
        m = m < OVFCAP ? m : OVFCAP;
        for (int tt = 0; tt < m; ++tt) {
            if (ovf_dst[tt] == i) addh(acc, gin[ovf_src[tt]]);
        }
    }
    // butterfly over the 6 components (all 8 lanes end with the total)
#pragma unroll
    for (int m = 1; m < 8; m <<= 1) {
#pragma unroll
        for (int f = 0; f < HID; ++f) acc[f] += __shfl_xor(acc[f], m);
    }
    if (sub != 0) return;
    float dv = dinv[i];
    float h[HID];
#pragma unroll
    for (int f = 0; f < HID; ++f) {
        float u = dv * acc[f] + b[f];
        h[f] = u > 0.0f ? u : 0.0f;
    }
    float o[HID];
    if (PREP) {
#pragma unroll
        for (int f = 0; f < HID; ++f) o[f] = dv * h[f];
    } else {
#pragma unroll
        for (int fo = 0; fo < HID; ++fo) {
            float s = 0.0f;
#pragma unroll
            for (int fi = 0; fi < HID; ++fi) s += h[fi] * W[fi * HID + fo];
            o[fo] = dv * s;
        }
    }
    gout[i] = packh(o);
}

// ---------------- pool: gather conv7 + Wf + relu + LDS mean-pool, 8 lanes per node ----------------
__global__ __launch_bounds__(256) void pool_kernel(
        const int* __restrict__ cnt, const int* __restrict__ ell,
        const int* __restrict__ ovf_meta, const int* __restrict__ ovf_dst,
        const int* __restrict__ ovf_src, const float* __restrict__ dinv,
        const uint4* __restrict__ gin, const int* __restrict__ batch,
        const float* __restrict__ Wf, const float* __restrict__ bf,
        float* __restrict__ pooled, float* __restrict__ gcnt, int N) {
    __shared__ float sp[NG * NC];
    __shared__ float sc[NG];
    __shared__ int srange[2];
    for (int k = threadIdx.x; k < NG * NC; k += 256) sp[k] = 0.0f;
    if (threadIdx.x < NG) sc[threadIdx.x] = 0.0f;
    int start = blockIdx.x * 32;           // 32 nodes per block (256 thr / 8)
    int endi = min(start + 32, N) - 1;
    if (threadIdx.x == 0) {
        srange[0] = batch[start];   // batch is sorted
        srange[1] = batch[endi];
    }
    __syncthreads();
    int t = blockIdx.x * 256 + threadIdx.x;
    int i = t >> 3;
    int sub = t & 7;
    if (i < N) {
        int n = cnt[i];
        int ne = n < SLOTS ? n : SLOTS;
        const int* er = ell + (size_t)i * SLOTS;
        float acc[HID] = {0.f, 0.f, 0.f, 0.f, 0.f, 0.f};
        gather8h(ne, er, gin, sub, acc);
        if (sub == 0) addh(acc, gin[i]);
        if (n > SLOTS && sub == 2) {
            int m = ovf_meta[0];
            m = m < OVFCAP ? m : OVFCAP;
            for (int tt = 0; tt < m; ++tt) {
                if (ovf_dst[tt] == i) addh(acc, gin[ovf_src[tt]]);
            }
        }
#pragma unroll
        for (int m = 1; m < 8; m <<= 1) {
#pragma unroll
            for (int f = 0; f < HID; ++f) acc[f] += __shfl_xor(acc[f], m);
        }
        if (sub == 0) {
            float dv = dinv[i];
            float u[HID];
#pragma unroll
            for (int f = 0; f < HID; ++f) u[f] = dv * acc[f];
            int bg = batch[i];
#pragma unroll
            for (int c = 0; c < NC; ++c) {
                float v = bf[c];
#pragma unroll
                for (int f = 0; f < HID; ++f) v += u[f] * Wf[f * NC + c];
                v = v > 0.0f ? v : 0.0f;
                atomicAdd(&sp[bg * NC + c], v);
            }
            atomicAdd(&sc[bg], 1.0f);
        }
    }
    __syncthreads();
    int bmin = srange[0], bmax = srange[1];
    int rows = bmax - bmin + 1;
    for (int k = threadIdx.x; k < rows * NC; k += 256) {
        int r = bmin + k / NC, c = k % NC;
        float v = sp[r * NC + c];
        if (v != 0.0f) atomicAdd(&pooled[r * NC + c], v);
    }
    for (int k = threadIdx.x; k < rows; k += 256) {
        float v = sc[bmin + k];
        if (v != 0.0f) atomicAdd(&gcnt[bmin + k], v);
    }
}

// ---------------- mean + log_softmax ----------------
__global__ void logsm_kernel(const float* __restrict__ pooled, const float* __restrict__ gcnt,
                             float* __restrict__ out) {
    int gidx = threadIdx.x;
    if (gidx >= NG) return;
    float c = gcnt[gidx];
    c = c > 1.0f ? c : 1.0f;
    float v[NC];
    float m = -1e30f;
#pragma unroll
    for (int k = 0; k < NC; ++k) {
        v[k] = pooled[gidx * NC + k] / c;
        m = v[k] > m ? v[k] : m;
    }
    float s = 0.0f;
#pragma unroll
    for (int k = 0; k < NC; ++k) s += expf(v[k] - m);
    float ls = logf(s);
#pragma unroll
    for (int k = 0; k < NC; ++k) out[gidx * NC + k] = v[k] - m - ls;
}

extern "C" void kernel_launch(void* const* d_in, const int* in_sizes, int n_in,
                              void* d_out, int out_size, void* d_ws, size_t ws_size,
                              hipStream_t stream) {
    const float* x     = (const float*)d_in[0];
    const int*   ei    = (const int*)d_in[1];
    const int*   batch = (const int*)d_in[2];
    const float* W[7];
    const float* b[7];
    for (int l = 0; l < 7; ++l) {
        W[l] = (const float*)d_in[3 + 2 * l];
        b[l] = (const float*)d_in[4 + 2 * l];
    }
    const int N = in_sizes[2];
    const int E = in_sizes[1] / 2;
    const int nbk = (N + BKT_NODES - 1) >> BKT_SH;
    const int* src = ei;
    const int* dst = ei + E;
    float* out = (float*)d_out;

    // workspace layout (16B-aligned blocks)
    char* wp = (char*)d_ws;
    int* bucket_cursor = (int*)wp;  wp += (size_t)NBK_MAX * 4;
    int* ovf_meta  = (int*)wp;      wp += 16;
    int* bovf_meta = (int*)wp;      wp += 16;   // metas contiguous with cursor -> one memset
    int* ovf_dst   = (int*)wp;      wp += OVFCAP * 4;
    int* ovf_src   = (int*)wp;      wp += OVFCAP * 4;
    int2* bovf     = (int2*)wp;     wp += (size_t)BOVFCAP * 8;
    int* cnt       = (int*)wp;      wp += (((size_t)N * 4 + 15) & ~15ull);
    float* dinv    = (float*)wp;    wp += (((size_t)N * 4 + 15) & ~15ull);
    uint4* g_a     = (uint4*)wp;    wp += (size_t)N * 16;
    uint4* g_b     = (uint4*)wp;    wp += (size_t)N * 16;
    float* pooled  = (float*)wp;    wp += NG * NC * 4;
    float* gcnt    = (float*)wp;    wp += (((size_t)NG * 4 + 15) & ~15ull);
    int* ell       = (int*)wp;      wp += (size_t)N * SLOTS * 4;
    unsigned int* bucket_arr = (unsigned int*)wp;  wp += (size_t)nbk * BCAP * 4;

    hipMemsetAsync(bucket_cursor, 0, (size_t)NBK_MAX * 4 + 32, stream);  // + both metas
    hipMemsetAsync(pooled, 0, (NG * NC + NG) * sizeof(float), stream);

    const int BT = 256;
    int bn8 = ((size_t)N * 8 + BT - 1) / BT;
    int bp1 = (E + EPB - 1) / EPB;

    bucket_scatter_kernel<<<bp1, BT, 0, stream>>>(src, dst, E, nbk, bucket_cursor,
                                                  bucket_arr, bovf_meta, bovf);
    ell_build_kernel<<<nbk, BT, 0, stream>>>(bucket_arr, bucket_cursor, bovf_meta, bovf,
                                             ell, cnt, dinv, ovf_meta, ovf_dst, ovf_src, N);

    layer1_kernel<<<bn8, BT, 0, stream>>>(x, W[0], dinv, g_a, N);

    // 5 mid layers: (b1,W2) .. (b5,W6), alternating g buffers
    gcn_layer8_kernel<0><<<bn8, BT, 0, stream>>>(cnt, ell, ovf_meta, ovf_dst, ovf_src, dinv, g_a, g_b, W[1], b[0], N);
    gcn_layer8_kernel<0><<<bn8, BT, 0, stream>>>(cnt, ell, ovf_meta, ovf_dst, ovf_src, dinv, g_b, g_a, W[2], b[1], N);
    gcn_layer8_kernel<0><<<bn8, BT, 0, stream>>>(cnt, ell, ovf_meta, ovf_dst, ovf_src, dinv, g_a, g_b, W[3], b[2], N);
    gcn_layer8_kernel<0><<<bn8, BT, 0, stream>>>(cnt, ell, ovf_meta, ovf_dst, ovf_src, dinv, g_b, g_a, W[4], b[3], N);
    gcn_layer8_kernel<0><<<bn8, BT, 0, stream>>>(cnt, ell, ovf_meta, ovf_dst, ovf_src, dinv, g_a, g_b, W[5], b[4], N);
    // layer 6 epilogue (b6), no next W
    gcn_layer8_kernel<1><<<bn8, BT, 0, stream>>>(cnt, ell, ovf_meta, ovf_dst, ovf_src, dinv, g_b, g_a, nullptr, b[5], N);
    // conv7 gather + Wf + bf + relu + pool
    pool_kernel<<<bn8, BT, 0, stream>>>(cnt, ell, ovf_meta, ovf_dst, ovf_src, dinv, g_a, batch, W[6], b[6], pooled, gcnt, N);
    logsm_kernel<<<1, 64, 0, stream>>>(pooled, gcnt, out);
}

// Round 9
// 345.272 us; speedup vs baseline: 1.1579x; 1.0238x over previous
//
#include <hip/hip_runtime.h>
#include <hip/hip_bf16.h>
#include <hip/hip_fp16.h>
#include <math.h>

#define NF     128
#define HID    6
#define NC     10
#define NG     64
#define SLOTS  64     // ELL row capacity (deg ~ Poisson(32); P(deg>64) ~ 4e-7/node)
#define OVFCAP 8192

// bucket build params
#define BKT_SH    7
#define BKT_NODES 128
#define NBK_MAX   1024     // supports N <= 131072
#define EPB       4096     // edges per phase-1 block (256 thr x 16)
#define BCAP      5120     // per-bucket capacity (mean 4096, +16 sigma)
#define BOVFCAP   4096

// g row: 6 values as fp16, padded to 16B (8 halves) -> ONE dwordx4 per neighbor.
// Accumulation in packed fp16 (3 x v_pk_add_f16 per neighbor).
__device__ __forceinline__ void addh2(__half2& a0, __half2& a1, __half2& a2, uint4 q) {
    const __half2* h = (const __half2*)&q;
    a0 = __hadd2(a0, h[0]);
    a1 = __hadd2(a1, h[1]);
    a2 = __hadd2(a2, h[2]);
}

__device__ __forceinline__ __half2 shfl_xor_h2(__half2 v, int m) {
    union { __half2 h; unsigned int u; } a;
    a.h = v;
    a.u = __shfl_xor(a.u, m);
    return a.h;
}

__device__ __forceinline__ uint4 packh(const float* v) {
    uint4 q;
    __half2* h = (__half2*)&q;
    h[0] = __floats2half2_rn(v[0], v[1]);
    h[1] = __floats2half2_rn(v[2], v[3]);
    h[2] = __floats2half2_rn(v[4], v[5]);
    h[3] = __floats2half2_rn(0.f, 0.f);
    return q;
}

// ---------------- phase 1: bin edges by dst>>7, rank-from-count, binary-search copy-out ----------------
__global__ __launch_bounds__(256) void bucket_scatter_kernel(
        const int* __restrict__ src, const int* __restrict__ dst, int E, int nbk,
        int* __restrict__ bucket_cursor, unsigned int* __restrict__ bucket_arr,
        int* __restrict__ bovf_meta, int2* __restrict__ bovf) {
    __shared__ int cntL[NBK_MAX];
    __shared__ int offs[NBK_MAX + 1];
    __shared__ int gb[NBK_MAX];
    __shared__ int wtot[4];
    __shared__ unsigned int stage[EPB];
    int tid = threadIdx.x;
    for (int k = tid; k < NBK_MAX; k += 256) cntL[k] = 0;
    __syncthreads();                                     // B1
    int e0 = blockIdx.x * EPB;
    int cnt_e = E - e0; if (cnt_e > EPB) cnt_e = EPB;
    int sreg[16], dreg[16], rank[16];
    // pass A: load edges + LDS-atomic rank (atomic return IS the local rank)
    if (cnt_e == EPB && (E & 3) == 0) {
        const int4* s4p = (const int4*)(src + e0);
        const int4* d4p = (const int4*)(dst + e0);
#pragma unroll
        for (int k = 0; k < 4; ++k) {
            int4 sv = s4p[k * 256 + tid];
            int4 dv = d4p[k * 256 + tid];
            sreg[4*k+0] = sv.x; sreg[4*k+1] = sv.y; sreg[4*k+2] = sv.z; sreg[4*k+3] = sv.w;
            dreg[4*k+0] = dv.x; dreg[4*k+1] = dv.y; dreg[4*k+2] = dv.z; dreg[4*k+3] = dv.w;
        }
#pragma unroll
        for (int k = 0; k < 16; ++k) rank[k] = atomicAdd(&cntL[dreg[k] >> BKT_SH], 1);
    } else {
#pragma unroll
        for (int k = 0; k < 16; ++k) {
            int e = e0 + k * 256 + tid;
            if (e < E) {
                dreg[k] = dst[e]; sreg[k] = src[e];
                rank[k] = atomicAdd(&cntL[dreg[k] >> BKT_SH], 1);
            } else dreg[k] = -1;
        }
    }
    __syncthreads();                                     // B2
    // exclusive scan over 1024 bucket counts: 4/thread + wave shfl-scan + wave-total combine
    int base = tid * 4;
    int c0 = cntL[base], c1 = cntL[base + 1], c2 = cntL[base + 2], c3 = cntL[base + 3];
    int tsum = c0 + c1 + c2 + c3;
    int lane = tid & 63, wv = tid >> 6;
    int v = tsum;
#pragma unroll
    for (int off = 1; off < 64; off <<= 1) {
        int u = __shfl_up(v, off);
        if (lane >= off) v += u;
    }
    if (lane == 63) wtot[wv] = v;
    __syncthreads();                                     // B3
    int wbase = 0;
    for (int w = 0; w < wv; ++w) wbase += wtot[w];
    int ex = wbase + v - tsum;
    offs[base]     = ex;
    offs[base + 1] = ex + c0;
    offs[base + 2] = ex + c0 + c1;
    offs[base + 3] = ex + c0 + c1 + c2;
    if (tid == 0) offs[NBK_MAX] = cnt_e;                 // sentinel
    // reserve global spans (one atomic per non-empty bucket per block)
    for (int bb = tid; bb < nbk; bb += 256) {
        int c = cntL[bb];
        if (c > 0) gb[bb] = atomicAdd(&bucket_cursor[bb], c);
    }
    __syncthreads();                                     // B4
    // pass B: direct-placed stage write (no second atomic)
#pragma unroll
    for (int k = 0; k < 16; ++k) {
        int d = dreg[k];
        if (d < 0) continue;
        int b = d >> BKT_SH;
        stage[offs[b] + rank[k]] =
            (unsigned int)(d & (BKT_NODES - 1)) | ((unsigned int)sreg[k] << BKT_SH);
    }
    __syncthreads();                                     // B5
    // copy out: bucket via binary search on offs (runs -> coalesced segments)
    for (int j = tid; j < cnt_e; j += 256) {
        unsigned int p = stage[j];
        int lo = 0, hi = NBK_MAX;
        while (hi - lo > 1) {
            int mid = (lo + hi) >> 1;
            if (offs[mid] <= j) lo = mid; else hi = mid;
        }
        int b = lo;
        int grel = gb[b] + (j - offs[b]);
        if (grel < BCAP) {
            bucket_arr[(size_t)b * BCAP + grel] = p;
        } else {  // bucket capacity overflow (~never)
            int d = (b << BKT_SH) | (int)(p & (BKT_NODES - 1));
            int s = (int)(p >> BKT_SH);
            int p2 = atomicAdd(bovf_meta, 1);
            if (p2 < BOVFCAP) bovf[p2] = make_int2(d, s);
        }
    }
}

// ---------------- phase 2: per-bucket ELL build in LDS, pruned coalesced dump + fused dinv ----------------
// ELL rows are padded (within the last occupied int4 chunk) with sentinel index N,
// which points at a zero row of g -> gathers add 4 unconditionally.
__global__ __launch_bounds__(256) void ell_build_kernel(
        const unsigned int* __restrict__ bucket_arr, const int* __restrict__ bucket_cursor,
        const int* __restrict__ bovf_meta, const int2* __restrict__ bovf,
        int* __restrict__ ell, int* __restrict__ cnt, float* __restrict__ dinv,
        int* __restrict__ ovf_meta, int* __restrict__ ovf_dst, int* __restrict__ ovf_src,
        int N) {
    __shared__ int ell_s[BKT_NODES * SLOTS];   // 32KB
    __shared__ int cur[BKT_NODES];
    int b = blockIdx.x;
    int tid = threadIdx.x;
    if (tid < BKT_NODES) cur[tid] = 0;
    for (int k = tid; k < BKT_NODES * SLOTS; k += 256) ell_s[k] = N;   // sentinel pad
    __syncthreads();
    int bc = bucket_cursor[b];
    if (bc > BCAP) bc = BCAP;
    const unsigned int* ba = bucket_arr + (size_t)b * BCAP;
    for (int j = tid; j < bc; j += 256) {
        unsigned int p = ba[j];
        int r = (int)(p & (BKT_NODES - 1));
        int s = (int)(p >> BKT_SH);
        int slot = atomicAdd(&cur[r], 1);
        if (slot < SLOTS) {
            ell_s[r * SLOTS + slot] = s;
        } else {  // node degree overflow (~never)
            int d = (b << BKT_SH) + r;
            int q = atomicAdd(ovf_meta, 1);
            if (q < OVFCAP) { ovf_dst[q] = d; ovf_src[q] = s; }
        }
    }
    // fold in bucket-capacity overflow edges (list is ~always empty)
    int m = *bovf_meta;
    if (m > BOVFCAP) m = BOVFCAP;
    for (int t = tid; t < m; t += 256) {
        int2 e = bovf[t];
        if ((e.x >> BKT_SH) == b) {
            int r = e.x & (BKT_NODES - 1);
            int slot = atomicAdd(&cur[r], 1);
            if (slot < SLOTS) {
                ell_s[r * SLOTS + slot] = e.y;
            } else {
                int q = atomicAdd(ovf_meta, 1);
                if (q < OVFCAP) { ovf_dst[q] = e.x; ovf_src[q] = e.y; }
            }
        }
    }
    __syncthreads();
    int nid0 = b << BKT_SH;
    int rows = N - nid0; if (rows > BKT_NODES) rows = BKT_NODES;
    if (rows <= 0) return;
    int4* eg = (int4*)(ell + (size_t)nid0 * SLOTS);
    const int4* es = (const int4*)ell_s;
    // dump only occupied int4 chunks (gathers never read past ceil(cnt/4) chunks)
    for (int k = tid; k < rows * (SLOTS / 4); k += 256) {
        int r = k >> 4;            // SLOTS/4 == 16 chunks per row
        int q = k & 15;
        int c = cur[r]; if (c > SLOTS) c = SLOTS;
        if (q * 4 < c) eg[k] = es[k];
    }
    for (int r = tid; r < rows; r += 256) {
        int deg = cur[r];
        cnt[nid0 + r] = deg;
        dinv[nid0 + r] = rsqrtf((float)deg + 1.0f);   // +1 self loop
    }
}

// ---------------- layer 1: g = dinv * (x @ W1), 8 lanes per node, fp16 row out ----------------
__global__ __launch_bounds__(256) void layer1_kernel(const float* __restrict__ x,
                                                     const float* __restrict__ W,
                                                     const float* __restrict__ dinv,
                                                     uint4* __restrict__ g16, int N) {
    __shared__ float sW[8 * 100];
    for (int idx = threadIdx.x; idx < NF * HID; idx += 256) {
        int s = idx / 96, r = idx % 96;
        int o = r / 16, j = r % 16;
        sW[s * 100 + o * 16 + j] = W[(s * 16 + j) * HID + o];
    }
    __syncthreads();
    int t = blockIdx.x * 256 + threadIdx.x;
    int i = t >> 3;
    int sub = t & 7;
    if (t == 0) g16[N] = make_uint4(0u, 0u, 0u, 0u);    // zero row for sentinel pads
    if (i >= N) return;
    const float4* xr = (const float4*)(x + (size_t)i * NF + sub * 16);
    float4 xv0 = xr[0], xv1 = xr[1], xv2 = xr[2], xv3 = xr[3];
    const float4* wr = (const float4*)(sW + sub * 100);
    float p[HID];
#pragma unroll
    for (int o = 0; o < HID; ++o) {
        float4 w0 = wr[o * 4 + 0], w1 = wr[o * 4 + 1], w2 = wr[o * 4 + 2], w3 = wr[o * 4 + 3];
        p[o] = xv0.x * w0.x + xv0.y * w0.y + xv0.z * w0.z + xv0.w * w0.w
             + xv1.x * w1.x + xv1.y * w1.y + xv1.z * w1.z + xv1.w * w1.w
             + xv2.x * w2.x + xv2.y * w2.y + xv2.z * w2.z + xv2.w * w2.w
             + xv3.x * w3.x + xv3.y * w3.y + xv3.z * w3.z + xv3.w * w3.w;
    }
#pragma unroll
    for (int m = 1; m < 8; m <<= 1) {
#pragma unroll
        for (int o = 0; o < HID; ++o) p[o] += __shfl_xor(p[o], m);
    }
    if (sub == 0) {
        float dv = dinv[i];
        float v[HID];
#pragma unroll
        for (int o = 0; o < HID; ++o) v[o] = dv * p[o];
        g16[i] = packh(v);
    }
}

// ---------------- chunked ELL gather (fp16 rows, fp16 accumulate, padded rows) ----------------
// sub-lane owns chunk [4*sub,4*sub+4) then [32+4*sub,...). All 4 entries added
// unconditionally; pads hit the zero row at index N.
__device__ __forceinline__ void gather8h(int ne, const int* __restrict__ er,
                                         const uint4* __restrict__ g16, int sub,
                                         __half2& a0, __half2& a1, __half2& a2) {
#pragma unroll
    for (int r = 0; r < SLOTS / 32; ++r) {
        int base = r * 32 + sub * 4;
        if (base < ne) {
            int4 q = *(const int4*)(er + base);
            uint4 v0 = g16[q.x];
            uint4 v1 = g16[q.y];
            uint4 v2 = g16[q.z];
            uint4 v3 = g16[q.w];
            addh2(a0, a1, a2, v0);
            addh2(a0, a1, a2, v1);
            addh2(a0, a1, a2, v2);
            addh2(a0, a1, a2, v3);
        }
    }
}

// ---------------- fused: gather + epilogue (+ next matmul), 8 lanes per node ----------------
// PREP=0: gout = dinv * (relu(dinv*(sum+self)+b) @ W)
// PREP=1: gout = dinv *  relu(dinv*(sum+self)+b)
template<int PREP>
__global__ __launch_bounds__(256) void gcn_layer8_kernel(
        const int* __restrict__ cnt, const int* __restrict__ ell,
        const int* __restrict__ ovf_meta, const int* __restrict__ ovf_dst,
        const int* __restrict__ ovf_src, const float* __restrict__ dinv,
        const uint4* __restrict__ gin, uint4* __restrict__ gout,
        const float* __restrict__ W, const float* __restrict__ b, int N) {
    int t = blockIdx.x * 256 + threadIdx.x;
    int i = t >> 3;
    int sub = t & 7;
    if (t == 0) gout[N] = make_uint4(0u, 0u, 0u, 0u);   // keep zero row alive
    if (i >= N) return;
    int n = cnt[i];
    int ne = n < SLOTS ? n : SLOTS;
    const int* er = ell + (size_t)i * SLOTS;
    __half2 a0 = __float2half2_rn(0.f), a1 = a0, a2 = a0;
    gather8h(ne, er, gin, sub, a0, a1, a2);
    // self-loop term, added exactly once across the subgroup
    if (sub == 0) addh2(a0, a1, a2, gin[i]);
    if (n > SLOTS && sub == 2) {  // ~never taken; correct fallback for deg>SLOTS
        int m = ovf_meta[0];
        m = m < OVFCAP ? m : OVFCAP;
        for (int tt = 0; tt < m; ++tt) {
            if (ovf_dst[tt] == i) addh2(a0, a1, a2, gin[ovf_src[tt]]);
        }
    }
    // packed butterfly (all 8 lanes end with the total)
#pragma unroll
    for (int m = 1; m < 8; m <<= 1) {
        a0 = __hadd2(a0, shfl_xor_h2(a0, m));
        a1 = __hadd2(a1, shfl_xor_h2(a1, m));
        a2 = __hadd2(a2, shfl_xor_h2(a2, m));
    }
    if (sub != 0) return;
    float2 f0 = __half22float2(a0), f1 = __half22float2(a1), f2 = __half22float2(a2);
    float acc[HID] = { f0.x, f0.y, f1.x, f1.y, f2.x, f2.y };
    float dv = dinv[i];
    float h[HID];
#pragma unroll
    for (int f = 0; f < HID; ++f) {
        float u = dv * acc[f] + b[f];
        h[f] = u > 0.0f ? u : 0.0f;
    }
    float o[HID];
    if (PREP) {
#pragma unroll
        for (int f = 0; f < HID; ++f) o[f] = dv * h[f];
    } else {
#pragma unroll
        for (int fo = 0; fo < HID; ++fo) {
            float s = 0.0f;
#pragma unroll
            for (int fi = 0; fi < HID; ++fi) s += h[fi] * W[fi * HID + fo];
            o[fo] = dv * s;
        }
    }
    gout[i] = packh(o);
}

// ---------------- pool: gather conv7 + Wf + relu + LDS mean-pool, 8 lanes per node ----------------
__global__ __launch_bounds__(256) void pool_kernel(
        const int* __restrict__ cnt, const int* __restrict__ ell,
        const int* __restrict__ ovf_meta, const int* __restrict__ ovf_dst,
        const int* __restrict__ ovf_src, const float* __restrict__ dinv,
        const uint4* __restrict__ gin, const int* __restrict__ batch,
        const float* __restrict__ Wf, const float* __restrict__ bf,
        float* __restrict__ pooled, float* __restrict__ gcnt, int N) {
    __shared__ float sp[NG * NC];
    __shared__ float sc[NG];
    __shared__ int srange[2];
    for (int k = threadIdx.x; k < NG * NC; k += 256) sp[k] = 0.0f;
    if (threadIdx.x < NG) sc[threadIdx.x] = 0.0f;
    int start = blockIdx.x * 32;           // 32 nodes per block (256 thr / 8)
    int endi = min(start + 32, N) - 1;
    if (threadIdx.x == 0) {
        srange[0] = batch[start];   // batch is sorted
        srange[1] = batch[endi];
    }
    __syncthreads();
    int t = blockIdx.x * 256 + threadIdx.x;
    int i = t >> 3;
    int sub = t & 7;
    if (i < N) {
        int n = cnt[i];
        int ne = n < SLOTS ? n : SLOTS;
        const int* er = ell + (size_t)i * SLOTS;
        __half2 a0 = __float2half2_rn(0.f), a1 = a0, a2 = a0;
        gather8h(ne, er, gin, sub, a0, a1, a2);
        if (sub == 0) addh2(a0, a1, a2, gin[i]);
        if (n > SLOTS && sub == 2) {
            int m = ovf_meta[0];
            m = m < OVFCAP ? m : OVFCAP;
            for (int tt = 0; tt < m; ++tt) {
                if (ovf_dst[tt] == i) addh2(a0, a1, a2, gin[ovf_src[tt]]);
            }
        }
#pragma unroll
        for (int m = 1; m < 8; m <<= 1) {
            a0 = __hadd2(a0, shfl_xor_h2(a0, m));
            a1 = __hadd2(a1, shfl_xor_h2(a1, m));
            a2 = __hadd2(a2, shfl_xor_h2(a2, m));
        }
        if (sub == 0) {
            float2 f0 = __half22float2(a0), f1 = __half22float2(a1), f2 = __half22float2(a2);
            float acc[HID] = { f0.x, f0.y, f1.x, f1.y, f2.x, f2.y };
            float dv = dinv[i];
            float u[HID];
#pragma unroll
            for (int f = 0; f < HID; ++f) u[f] = dv * acc[f];
            int bg = batch[i];
#pragma unroll
            for (int c = 0; c < NC; ++c) {
                float v = bf[c];
#pragma unroll
                for (int f = 0; f < HID; ++f) v += u[f] * Wf[f * NC + c];
                v = v > 0.0f ? v : 0.0f;
                atomicAdd(&sp[bg * NC + c], v);
            }
            atomicAdd(&sc[bg], 1.0f);
        }
    }
    __syncthreads();
    int bmin = srange[0], bmax = srange[1];
    int rows = bmax - bmin + 1;
    for (int k = threadIdx.x; k < rows * NC; k += 256) {
        int r = bmin + k / NC, c = k % NC;
        float v = sp[r * NC + c];
        if (v != 0.0f) atomicAdd(&pooled[r * NC + c], v);
    }
    for (int k = threadIdx.x; k < rows; k += 256) {
        float v = sc[bmin + k];
        if (v != 0.0f) atomicAdd(&gcnt[bmin + k], v);
    }
}

// ---------------- mean + log_softmax ----------------
__global__ void logsm_kernel(const float* __restrict__ pooled, const float* __restrict__ gcnt,
                             float* __restrict__ out) {
    int gidx = threadIdx.x;
    if (gidx >= NG) return;
    float c = gcnt[gidx];
    c = c > 1.0f ? c : 1.0f;
    float v[NC];
    float m = -1e30f;
#pragma unroll
    for (int k = 0; k < NC; ++k) {
        v[k] = pooled[gidx * NC + k] / c;
        m = v[k] > m ? v[k] : m;
    }
    float s = 0.0f;
#pragma unroll
    for (int k = 0; k < NC; ++k) s += expf(v[k] - m);
    float ls = logf(s);
#pragma unroll
    for (int k = 0; k < NC; ++k) out[gidx * NC + k] = v[k] - m - ls;
}

extern "C" void kernel_launch(void* const* d_in, const int* in_sizes, int n_in,
                              void* d_out, int out_size, void* d_ws, size_t ws_size,
                              hipStream_t stream) {
    const float* x     = (const float*)d_in[0];
    const int*   ei    = (const int*)d_in[1];
    const int*   batch = (const int*)d_in[2];
    const float* W[7];
    const float* b[7];
    for (int l = 0; l < 7; ++l) {
        W[l] = (const float*)d_in[3 + 2 * l];
        b[l] = (const float*)d_in[4 + 2 * l];
    }
    const int N = in_sizes[2];
    const int E = in_sizes[1] / 2;
    const int nbk = (N + BKT_NODES - 1) >> BKT_SH;
    const int* src = ei;
    const int* dst = ei + E;
    float* out = (float*)d_out;

    // workspace layout (16B-aligned blocks)
    char* wp = (char*)d_ws;
    int* bucket_cursor = (int*)wp;  wp += (size_t)NBK_MAX * 4;
    int* ovf_meta  = (int*)wp;      wp += 16;
    int* bovf_meta = (int*)wp;      wp += 16;   // metas contiguous with cursor -> one memset
    int* ovf_dst   = (int*)wp;      wp += OVFCAP * 4;
    int* ovf_src   = (int*)wp;      wp += OVFCAP * 4;
    int2* bovf     = (int2*)wp;     wp += (size_t)BOVFCAP * 8;
    int* cnt       = (int*)wp;      wp += (((size_t)N * 4 + 15) & ~15ull);
    float* dinv    = (float*)wp;    wp += (((size_t)N * 4 + 15) & ~15ull);
    uint4* g_a     = (uint4*)wp;    wp += (size_t)(N + 1) * 16;   // +1: zero row for pads
    uint4* g_b     = (uint4*)wp;    wp += (size_t)(N + 1) * 16;
    float* pooled  = (float*)wp;    wp += NG * NC * 4;
    float* gcnt    = (float*)wp;    wp += (((size_t)NG * 4 + 15) & ~15ull);
    int* ell       = (int*)wp;      wp += (size_t)N * SLOTS * 4;
    unsigned int* bucket_arr = (unsigned int*)wp;  wp += (size_t)nbk * BCAP * 4;

    hipMemsetAsync(bucket_cursor, 0, (size_t)NBK_MAX * 4 + 32, stream);  // + both metas
    hipMemsetAsync(pooled, 0, (NG * NC + NG) * sizeof(float), stream);

    const int BT = 256;
    int bn8 = ((size_t)N * 8 + BT - 1) / BT;
    int bp1 = (E + EPB - 1) / EPB;

    bucket_scatter_kernel<<<bp1, BT, 0, stream>>>(src, dst, E, nbk, bucket_cursor,
                                                  bucket_arr, bovf_meta, bovf);
    ell_build_kernel<<<nbk, BT, 0, stream>>>(bucket_arr, bucket_cursor, bovf_meta, bovf,
                                             ell, cnt, dinv, ovf_meta, ovf_dst, ovf_src, N);

    layer1_kernel<<<bn8, BT, 0, stream>>>(x, W[0], dinv, g_a, N);

    // 5 mid layers: (b1,W2) .. (b5,W6), alternating g buffers
    gcn_layer8_kernel<0><<<bn8, BT, 0, stream>>>(cnt, ell, ovf_meta, ovf_dst, ovf_src, dinv, g_a, g_b, W[1], b[0], N);
    gcn_layer8_kernel<0><<<bn8, BT, 0, stream>>>(cnt, ell, ovf_meta, ovf_dst, ovf_src, dinv, g_b, g_a, W[2], b[1], N);
    gcn_layer8_kernel<0><<<bn8, BT, 0, stream>>>(cnt, ell, ovf_meta, ovf_dst, ovf_src, dinv, g_a, g_b, W[3], b[2], N);
    gcn_layer8_kernel<0><<<bn8, BT, 0, stream>>>(cnt, ell, ovf_meta, ovf_dst, ovf_src, dinv, g_b, g_a, W[4], b[3], N);
    gcn_layer8_kernel<0><<<bn8, BT, 0, stream>>>(cnt, ell, ovf_meta, ovf_dst, ovf_src, dinv, g_a, g_b, W[5], b[4], N);
    // layer 6 epilogue (b6), no next W
    gcn_layer8_kernel<1><<<bn8, BT, 0, stream>>>(cnt, ell, ovf_meta, ovf_dst, ovf_src, dinv, g_b, g_a, nullptr, b[5], N);
    // conv7 gather + Wf + bf + relu + pool
    pool_kernel<<<bn8, BT, 0, stream>>>(cnt, ell, ovf_meta, ovf_dst, ovf_src, dinv, g_a, batch, W[6], b[6], pooled, gcnt, N);
    logsm_kernel<<<1, 64, 0, stream>>>(pooled, gcnt, out);
}